// Round 1
// baseline (167.874 us; speedup 1.0000x reference)
//
#include <hip/hip_runtime.h>

// Problem constants
#define DD 64
#define LL 50
#define NB 4096
#define NT 100

typedef __attribute__((ext_vector_type(8))) __bf16 bf16x8;
typedef __attribute__((ext_vector_type(4))) float f32x4;

__device__ __forceinline__ float sigmoidf_(float x) {
    return 1.0f / (1.0f + __expf(-x));
}
// round-half-up f32->bf16, pack two into one u32 (hi -> upper 16)
__device__ __forceinline__ unsigned pack_bf16(float hi, float lo) {
    union { float f; unsigned u; } a, b;
    a.f = hi; b.f = lo;
    return ((a.u + 0x8000u) & 0xffff0000u) | ((b.u + 0x8000u) >> 16);
}
__device__ __forceinline__ uint4 cvt8u(const float* f) {
    uint4 r;
    r.x = pack_bf16(f[1], f[0]);
    r.y = pack_bf16(f[3], f[2]);
    r.z = pack_bf16(f[5], f[4]);
    r.w = pack_bf16(f[7], f[6]);
    return r;
}
__device__ __forceinline__ bf16x8 cvt8(const float* f) {
    return __builtin_bit_cast(bf16x8, cvt8u(f));
}
// async global->LDS: wave-uniform LDS base + lane*size (gfx950)
__device__ __forceinline__ void glds16(const float* g, float* l) {
    __builtin_amdgcn_global_load_lds(
        (const __attribute__((address_space(1))) void*)g,
        (__attribute__((address_space(3))) void*)l, 16, 0, 0);
}
__device__ __forceinline__ void glds4(const float* g, float* l) {
    __builtin_amdgcn_global_load_lds(
        (const __attribute__((address_space(1))) void*)g,
        (__attribute__((address_space(3))) void*)l, 4, 0, 0);
}

// ===========================================================================
// K0: blocks 0..255: batched user GEMM (16 users/block, 2 waves: wave 0 does
//     ni 0..3 (fg_user_W), wave 1 does ni 4..7 (inst_gate_user)).
//     block 256: pack fg_item_W -> bf16 row-major (k1 reads frags directly).
// ===========================================================================
__global__ __launch_bounds__(128) void k0_user(
    const int* __restrict__ uid_g, const float* __restrict__ user_table,
    const float* __restrict__ Wu, const float* __restrict__ bu,
    const float* __restrict__ bi, const float* __restrict__ igu,
    const float* __restrict__ Wi,
    float* __restrict__ ufg_ws, float* __restrict__ t2_ws,
    unsigned short* __restrict__ wiB_ws)
{
    if (blockIdx.x == 256) {   // Wi -> bf16 pack (one wave only)
        if (threadIdx.x >= 64) return;
        const int n = threadIdx.x;
        float tmp[64];
#pragma unroll
        for (int c4 = 0; c4 < 16; c4++)
            *(float4*)&tmp[c4 * 4] = *(const float4*)(Wi + n * DD + c4 * 4);
#pragma unroll
        for (int ch = 0; ch < 8; ch++)
            *(uint4*)(wiB_ws + n * DD + ch * 8) = cvt8u(tmp + ch * 8);
        return;
    }

    const int lane = threadIdx.x & 63;
    const int wv = threadIdx.x >> 6;         // wave 0: ni 0..3, wave 1: ni 4..7
    const int c = lane & 15, q = lane >> 4;
    const int uid = uid_g[blockIdx.x * 16 + c];
    const float* urow = user_table + (size_t)uid * DD;

    bf16x8 af[2];
#pragma unroll
    for (int kf = 0; kf < 2; kf++) {
        float tmp[8];
        *(float4*)&tmp[0] = *(const float4*)(urow + kf * 32 + q * 8);
        *(float4*)&tmp[4] = *(const float4*)(urow + kf * 32 + q * 8 + 4);
        af[kf] = cvt8(tmp);
    }

#pragma unroll
    for (int ni0 = 0; ni0 < 4; ni0++) {
        const int ni = wv * 4 + ni0;
        f32x4 a = {0.f, 0.f, 0.f, 0.f};
#pragma unroll
        for (int kf = 0; kf < 2; kf++) {
            const int k0 = kf * 32 + q * 8;
            float tmp[8];
            if (ni < 4) {
                const float* src = Wu + (ni * 16 + c) * DD + k0;
                *(float4*)&tmp[0] = *(const float4*)src;
                *(float4*)&tmp[4] = *(const float4*)(src + 4);
            } else {
                const int l = ni * 16 + c - 64;
#pragma unroll
                for (int j = 0; j < 8; j++)
                    tmp[j] = (l < LL) ? igu[(k0 + j) * LL + l] : 0.f;
            }
            a = __builtin_amdgcn_mfma_f32_16x16x32_bf16(af[kf], cvt8(tmp), a, 0, 0, 0);
        }
        const int n = ni * 16 + c;
#pragma unroll
        for (int reg = 0; reg < 4; reg++) {
            const int bo = blockIdx.x * 16 + q * 4 + reg;
            if (n < DD)           ufg_ws[bo * DD + n] = a[reg] + bu[n] + bi[n];
            else if (n < DD + LL) t2_ws[bo * DD + (n - DD)] = a[reg];
        }
    }
}

// ===========================================================================
// K1F: fused union + scoring. One block of 256 threads (4 waves) per b.
//   Phase A (all waves): issue ALL async gathers up front —
//     13 glds16 item rows (XOR-swizzled), 25 glds16 W2 rows (linear),
//     2 glds4 b2, 1 glds4 t2. W2 latency hides under union compute.
//   Phase B: union, mi-loop split across 4 waves (8 MFMA each),
//     cross-wave reduce of unum/sip/isum via LDS -> sV.
//   Phase C: all waves score 112 target slots from LDS (full-row b128
//     reads are at the LDS 1KB/instr bandwidth floor; swizzle can't help).
// ===========================================================================
__global__ __launch_bounds__(256) void k1_fused(
    const int* __restrict__ uid_g, const int* __restrict__ iid_g,
    const int* __restrict__ tgt_g,
    const float* __restrict__ user_table, const float* __restrict__ item_table,
    const float* __restrict__ W2, const float* __restrict__ b2,
    const unsigned short* __restrict__ wiB, const float* __restrict__ igi,
    const float* __restrict__ ufg_ws, const float* __restrict__ t2_ws,
    float* __restrict__ out)
{
    const int tid = threadIdx.x;
    const int lane = tid & 63;
    const int w = tid >> 6;                 // wave id 0..3 == union mi
    const int c = lane & 15, q = lane >> 4;
    const int b = blockIdx.x;

    __shared__ __align__(16) float sE[52 * DD];     // item rows, XOR-swizzled
    __shared__ __align__(16) float sW[112 * DD];    // W2 rows (100 real + 12 pad)
    __shared__ __align__(16) float sT[DD];          // t2
    __shared__ __align__(16) float sB[128];         // b2
    __shared__ __align__(16) float sU[4 * DD];      // per-wave unum partial (d)
    __shared__ __align__(16) float sS[4 * DD];      // per-wave sip partial (d)
    __shared__ float sI[4];                          // per-wave isum partial
    __shared__ __align__(16) float sV[DD];          // final user vector
    __shared__ float sOut[112];

    const int* iidp = iid_g + b * LL;
    const int* tgtp = tgt_g + b * NT;

    // ---- item ids (clamped) + async item gather, distributed: wave w takes
    //      s = w, w+4, w+8 (+ s=12 on wave 0). Rows 4s..4s+3, 256B each,
    //      16B chunks XOR-swizzled by (row&7) on the global side. ----
    int iid3[3];
#pragma unroll
    for (int k = 0; k < 3; k++) {
        const int s = w + 4 * k;
        const int r = 4 * s + (lane >> 4);
        iid3[k] = iidp[r < LL ? r : LL - 1];
    }
    int iid12 = 0;
    if (w == 0) {
        const int r = 48 + (lane >> 4);
        iid12 = iidp[r < LL ? r : LL - 1];
    }
#pragma unroll
    for (int k = 0; k < 3; k++) {
        const int s = w + 4 * k;
        const int r = 4 * s + (lane >> 4);
        const int j2 = (lane & 15) ^ (r & 7);
        glds16(item_table + (size_t)iid3[k] * DD + j2 * 4, sE + s * 256);
    }
    if (w == 0) {
        const int r = 48 + (lane >> 4);
        const int j2 = (lane & 15) ^ (r & 7);
        glds16(item_table + (size_t)iid12 * DD + j2 * 4, sE + 12 * 256);
    }

    // ---- target ids + async W2 gather: 25 instrs cover rows 0..99 exactly.
    //      wave w takes s2 = w, w+4, ..., w+20 (+ s2=24 on wave 0). ----
    int tids6[6];
#pragma unroll
    for (int i = 0; i < 6; i++) {
        const int s2 = w + 4 * i;               // 0..23 -> rows 0..95
        tids6[i] = tgtp[4 * s2 + (lane >> 4)];
    }
    int tid24 = 0;
    if (w == 0) tid24 = tgtp[96 + (lane >> 4)];  // rows 96..99
#pragma unroll
    for (int i = 0; i < 6; i++) {
        const int s2 = w + 4 * i;
        glds16(W2 + (size_t)tids6[i] * DD + (lane & 15) * 4, sW + s2 * 256);
    }
    if (w == 0)
        glds16(W2 + (size_t)tid24 * DD + (lane & 15) * 4, sW + 24 * 256);

    // ---- b2 (waves 0,1) and t2 (wave 1), 4B async each ----
    if (w < 2) {
        const int sl = w * 64 + lane;
        const int tb = sl < NT ? sl : NT - 1;
        glds4(b2 + tgtp[tb], sB + w * 64);
    }
    if (w == 1)
        glds4(t2_ws + b * DD + (lane < LL ? lane : LL - 1), sT);

    // ---- independent register loads (overlap all gathers) ----
    bf16x8 wb[4][2];
#pragma unroll
    for (int ni = 0; ni < 4; ni++)
#pragma unroll
        for (int kf = 0; kf < 2; kf++)
            wb[ni][kf] = __builtin_bit_cast(bf16x8,
                *(const uint4*)(wiB + (ni * 16 + c) * DD + kf * 32 + q * 8));

    float ufg4[4], igi4[4];
#pragma unroll
    for (int ni = 0; ni < 4; ni++) {
        ufg4[ni] = ufg_ws[b * DD + ni * 16 + c];
        igi4[ni] = igi[ni * 16 + c];
    }
    float u = 0.f;
    if (w == 0) {
        const int uid = uid_g[b];
        u = user_table[(size_t)uid * DD + lane];
    }

    __syncthreads();   // each wave drains its own vmcnt -> all LDS visible

    // ---- union: this wave owns row-group mi == w (rows w*16 .. w*16+15) ----
    bf16x8 ea[2];
    {
        const int row = w * 16 + c;
        const int rr = (row < LL) ? row : 0;
        const float* rowp = sE + rr * DD;
        const int s7 = rr & 7;
#pragma unroll
        for (int kf = 0; kf < 2; kf++) {
            float tmp[8];
            const int ch0 = (kf * 8 + 2 * q) ^ s7;
            const int ch1 = (kf * 8 + 2 * q + 1) ^ s7;
            *(float4*)&tmp[0] = *(const float4*)(rowp + ch0 * 4);
            *(float4*)&tmp[4] = *(const float4*)(rowp + ch1 * 4);
            if (row >= LL) {
#pragma unroll
                for (int i = 0; i < 8; i++) tmp[i] = 0.f;
            }
            ea[kf] = cvt8(tmp);
        }
    }

    float unum[4] = {0.f, 0.f, 0.f, 0.f};
    float sip[4]  = {0.f, 0.f, 0.f, 0.f};
    float isum = 0.f;
    {
        f32x4 acc[4];
#pragma unroll
        for (int ni = 0; ni < 4; ni++) {
            f32x4 a = {0.f, 0.f, 0.f, 0.f};
            a = __builtin_amdgcn_mfma_f32_16x16x32_bf16(ea[0], wb[ni][0], a, 0, 0, 0);
            a = __builtin_amdgcn_mfma_f32_16x16x32_bf16(ea[1], wb[ni][1], a, 0, 0, 0);
            acc[ni] = a;
        }
        float gated[4][4], inst_r[4];
#pragma unroll
        for (int reg = 0; reg < 4; reg++) {
            const int l = w * 16 + q * 4 + reg;
            const int valid = (l < LL);
            const int lr = valid ? l : 0;
            const int s7 = lr & 7;
            float t1 = 0.f;
#pragma unroll
            for (int ni = 0; ni < 4; ni++) {
                const int phys = (4 * ni + (c >> 2)) ^ s7;
                const float ev = sE[lr * DD + phys * 4 + (c & 3)];
                const float e = valid ? ev : 0.f;
                const float g = sigmoidf_(acc[ni][reg] + ufg4[ni]);
                const float gd = e * g;
                gated[reg][ni] = gd;
                t1 += gd * igi4[ni];
                sip[ni] += e;
            }
            t1 += __shfl_xor(t1, 1); t1 += __shfl_xor(t1, 2);
            t1 += __shfl_xor(t1, 4); t1 += __shfl_xor(t1, 8);
            inst_r[reg] = valid ? sigmoidf_(t1 + sT[lr]) : 0.f;
        }
#pragma unroll
        for (int reg = 0; reg < 4; reg++) {
            isum += inst_r[reg];
#pragma unroll
            for (int ni = 0; ni < 4; ni++)
                unum[ni] += gated[reg][ni] * inst_r[reg];
        }
    }

    // intra-wave: sum over q groups, then pick ni == q -> value for d = lane
#pragma unroll
    for (int ni = 0; ni < 4; ni++) {
        unum[ni] += __shfl_xor(unum[ni], 16); unum[ni] += __shfl_xor(unum[ni], 32);
        sip[ni]  += __shfl_xor(sip[ni], 16);  sip[ni]  += __shfl_xor(sip[ni], 32);
    }
    isum += __shfl_xor(isum, 16); isum += __shfl_xor(isum, 32);

    const float un = (q == 0) ? unum[0] : (q == 1) ? unum[1] : (q == 2) ? unum[2] : unum[3];
    const float si = (q == 0) ? sip[0]  : (q == 1) ? sip[1]  : (q == 2) ? sip[2]  : sip[3];
    sU[w * DD + lane] = un;
    sS[w * DD + lane] = si;
    if (lane == 0) sI[w] = isum;
    __syncthreads();

    if (w == 0) {
        const float unt = sU[lane] + sU[DD + lane] + sU[2 * DD + lane] + sU[3 * DD + lane];
        const float sit = sS[lane] + sS[DD + lane] + sS[2 * DD + lane] + sS[3 * DD + lane];
        const float ist = sI[0] + sI[1] + sI[2] + sI[3];
        sV[lane] = u + unt / ist + sit;
    }
    __syncthreads();

    // ---- scoring: 16 lanes per target slot, 7 slots per 16-lane group ----
    const int j = tid & 15, gg = tid >> 4;
    const float4 vr = *(const float4*)&sV[j * 4];
#pragma unroll
    for (int i = 0; i < 7; i++) {
        const int ts = i * 16 + gg;             // 0..111 (100..111 = pad)
        const float4 wvv = *(const float4*)&sW[ts * DD + j * 4];
        float s = wvv.x * vr.x + wvv.y * vr.y + wvv.z * vr.z + wvv.w * vr.w;
        s += __shfl_xor(s, 1); s += __shfl_xor(s, 2);
        s += __shfl_xor(s, 4); s += __shfl_xor(s, 8);
        if (j == 0 && ts < NT) sOut[ts] = s + sB[ts];
    }
    __syncthreads();
    if (tid < NT) out[b * NT + tid] = sOut[tid];
}

// ===========================================================================
extern "C" void kernel_launch(void* const* d_in, const int* in_sizes, int n_in,
                              void* d_out, int out_size, void* d_ws, size_t ws_size,
                              hipStream_t stream)
{
    const int* user_ids        = (const int*)d_in[0];
    const int* item_seq_ids    = (const int*)d_in[1];
    const int* target_item_ids = (const int*)d_in[2];
    const float* user_tab      = (const float*)d_in[3];
    const float* item_tab      = (const float*)d_in[4];
    const float* W2_tab        = (const float*)d_in[5];
    const float* b2_tab        = (const float*)d_in[6];
    const float* fg_item_W     = (const float*)d_in[7];
    const float* fg_item_b     = (const float*)d_in[8];
    const float* fg_user_W     = (const float*)d_in[9];
    const float* fg_user_b     = (const float*)d_in[10];
    const float* igi           = (const float*)d_in[11];
    const float* igu           = (const float*)d_in[12];
    float* out = (float*)d_out;

    float* ufg_ws = (float*)d_ws;                       // [4096][64] f32
    float* t2_ws  = ufg_ws + NB * DD;                   // [4096][64] f32
    unsigned short* wiB_ws = (unsigned short*)(t2_ws + NB * DD);  // [64][64] bf16

    k0_user<<<257, 128, 0, stream>>>(user_ids, user_tab, fg_user_W, fg_user_b,
                                     fg_item_b, igu, fg_item_W,
                                     ufg_ws, t2_ws, wiB_ws);
    k1_fused<<<NB, 256, 0, stream>>>(user_ids, item_seq_ids, target_item_ids,
                                     user_tab, item_tab, W2_tab, b2_tab,
                                     wiB_ws, igi, ufg_ws, t2_ws, out);
}

// Round 2
// 154.554 us; speedup vs baseline: 1.0862x; 1.0862x over previous
//
#include <hip/hip_runtime.h>

// Problem constants
#define DD 64
#define LL 50
#define NB 4096
#define NT 100

typedef __attribute__((ext_vector_type(8))) __bf16 bf16x8;
typedef __attribute__((ext_vector_type(4))) float f32x4;

__device__ __forceinline__ float sigmoidf_(float x) {
    // v_rcp_f32 (~1ulp) instead of precise-division sequence (~10 instrs)
    return __builtin_amdgcn_rcpf(1.0f + __expf(-x));
}
// round-half-up f32->bf16, pack two into one u32 (hi -> upper 16)  [k0 path]
__device__ __forceinline__ unsigned pack_bf16(float hi, float lo) {
    union { float f; unsigned u; } a, b;
    a.f = hi; b.f = lo;
    return ((a.u + 0x8000u) & 0xffff0000u) | ((b.u + 0x8000u) >> 16);
}
__device__ __forceinline__ uint4 cvt8u(const float* f) {
    uint4 r;
    r.x = pack_bf16(f[1], f[0]);
    r.y = pack_bf16(f[3], f[2]);
    r.z = pack_bf16(f[5], f[4]);
    r.w = pack_bf16(f[7], f[6]);
    return r;
}
__device__ __forceinline__ bf16x8 cvt8(const float* f) {
    return __builtin_bit_cast(bf16x8, cvt8u(f));
}
// HW packed RNE convert: dst.lo = bf16(lo), dst.hi = bf16(hi)  [k1 path]
__device__ __forceinline__ unsigned cvtpk(float lo, float hi) {
    unsigned r;
    asm("v_cvt_pk_bf16_f32 %0, %1, %2" : "=v"(r) : "v"(lo), "v"(hi));
    return r;
}
__device__ __forceinline__ bf16x8 cvt8f(const float* f) {
    uint4 r;
    r.x = cvtpk(f[0], f[1]);
    r.y = cvtpk(f[2], f[3]);
    r.z = cvtpk(f[4], f[5]);
    r.w = cvtpk(f[6], f[7]);
    return __builtin_bit_cast(bf16x8, r);
}
// async global->LDS: wave-uniform LDS base + lane*size (gfx950)
__device__ __forceinline__ void glds16(const float* g, float* l) {
    __builtin_amdgcn_global_load_lds(
        (const __attribute__((address_space(1))) void*)g,
        (__attribute__((address_space(3))) void*)l, 16, 0, 0);
}
__device__ __forceinline__ void glds4(const float* g, float* l) {
    __builtin_amdgcn_global_load_lds(
        (const __attribute__((address_space(1))) void*)g,
        (__attribute__((address_space(3))) void*)l, 4, 0, 0);
}

// ===========================================================================
// K0: blocks 0..255: batched user GEMM (16 users/block, 2 waves: wave 0 does
//     ni 0..3 (fg_user_W), wave 1 does ni 4..7 (inst_gate_user)).
//     block 256: pack fg_item_W -> bf16 row-major (k1 reads frags directly).
// ===========================================================================
__global__ __launch_bounds__(128) void k0_user(
    const int* __restrict__ uid_g, const float* __restrict__ user_table,
    const float* __restrict__ Wu, const float* __restrict__ bu,
    const float* __restrict__ bi, const float* __restrict__ igu,
    const float* __restrict__ Wi,
    float* __restrict__ ufg_ws, float* __restrict__ t2_ws,
    unsigned short* __restrict__ wiB_ws)
{
    if (blockIdx.x == 256) {   // Wi -> bf16 pack (one wave only)
        if (threadIdx.x >= 64) return;
        const int n = threadIdx.x;
        float tmp[64];
#pragma unroll
        for (int c4 = 0; c4 < 16; c4++)
            *(float4*)&tmp[c4 * 4] = *(const float4*)(Wi + n * DD + c4 * 4);
#pragma unroll
        for (int ch = 0; ch < 8; ch++)
            *(uint4*)(wiB_ws + n * DD + ch * 8) = cvt8u(tmp + ch * 8);
        return;
    }

    const int lane = threadIdx.x & 63;
    const int wv = threadIdx.x >> 6;         // wave 0: ni 0..3, wave 1: ni 4..7
    const int c = lane & 15, q = lane >> 4;
    const int uid = uid_g[blockIdx.x * 16 + c];
    const float* urow = user_table + (size_t)uid * DD;

    bf16x8 af[2];
#pragma unroll
    for (int kf = 0; kf < 2; kf++) {
        float tmp[8];
        *(float4*)&tmp[0] = *(const float4*)(urow + kf * 32 + q * 8);
        *(float4*)&tmp[4] = *(const float4*)(urow + kf * 32 + q * 8 + 4);
        af[kf] = cvt8(tmp);
    }

#pragma unroll
    for (int ni0 = 0; ni0 < 4; ni0++) {
        const int ni = wv * 4 + ni0;
        f32x4 a = {0.f, 0.f, 0.f, 0.f};
#pragma unroll
        for (int kf = 0; kf < 2; kf++) {
            const int k0 = kf * 32 + q * 8;
            float tmp[8];
            if (ni < 4) {
                const float* src = Wu + (ni * 16 + c) * DD + k0;
                *(float4*)&tmp[0] = *(const float4*)src;
                *(float4*)&tmp[4] = *(const float4*)(src + 4);
            } else {
                const int l = ni * 16 + c - 64;
#pragma unroll
                for (int j = 0; j < 8; j++)
                    tmp[j] = (l < LL) ? igu[(k0 + j) * LL + l] : 0.f;
            }
            a = __builtin_amdgcn_mfma_f32_16x16x32_bf16(af[kf], cvt8(tmp), a, 0, 0, 0);
        }
        const int n = ni * 16 + c;
#pragma unroll
        for (int reg = 0; reg < 4; reg++) {
            const int bo = blockIdx.x * 16 + q * 4 + reg;
            if (n < DD)           ufg_ws[bo * DD + n] = a[reg] + bu[n] + bi[n];
            else if (n < DD + LL) t2_ws[bo * DD + (n - DD)] = a[reg];
        }
    }
}

// ===========================================================================
// K1F: fused union + scoring. 256 threads (4 waves) per b.
//   Occupancy-first redesign: W2 rows live in REGISTERS (wv[7] float4/thread,
//   T14 issue-early/consume-late), not LDS. LDS = item tile + small buffers
//   (~17 KB), __launch_bounds__(256,4) caps VGPR at 128 -> 4 blocks/CU
//   (vs 3 blocks at 45.5 KB LDS before).
//   Phase A: issue 13 item glds16 (XOR-swizzled) + W2 reg gathers + b2/t2/u
//   glds4 — one latency window for everything.
//   Phase B: union, mi == wave id; per-reg fused epilogue (no gated[4][4]).
//   Cross-wave reduce via sU/sS/sI; all threads redundantly fold to vr
//   (saves a barrier + wave0-only serialization).
//   Phase C: score from registers, stage 100 floats, coalesced store.
// ===========================================================================
__global__ __launch_bounds__(256, 4) void k1_fused(
    const int* __restrict__ uid_g, const int* __restrict__ iid_g,
    const int* __restrict__ tgt_g,
    const float* __restrict__ user_table, const float* __restrict__ item_table,
    const float* __restrict__ W2, const float* __restrict__ b2,
    const unsigned short* __restrict__ wiB, const float* __restrict__ igi,
    const float* __restrict__ ufg_ws, const float* __restrict__ t2_ws,
    float* __restrict__ out)
{
    const int tid = threadIdx.x;
    const int lane = tid & 63;
    const int w = tid >> 6;                 // wave id 0..3 == union mi
    const int c = lane & 15, q = lane >> 4;
    const int j = tid & 15, gg = tid >> 4;  // scoring: 16 groups of 16 lanes
    const int b = blockIdx.x;

    __shared__ __align__(16) float sE[52 * DD];   // item rows, XOR-swizzled
    __shared__ __align__(16) float sT[DD];        // t2
    __shared__ __align__(16) float sB[128];       // b2
    __shared__ __align__(16) float sU[4 * DD];    // per-wave unum partials
    __shared__ __align__(16) float sS[4 * DD];    // per-wave sip partials
    __shared__ __align__(16) float sUu[DD];       // user row
    __shared__ float sI[4];                       // per-wave isum partials
    __shared__ float sOut[112];

    const int* iidp = iid_g + b * LL;
    const int* tgtp = tgt_g + b * NT;

    // ---- item ids (clamped) + async gather: wave w takes s = w, w+4, w+8
    //      (+ s=12 on wave 0). Rows 4s..4s+3, 16B chunks XOR-swizzled by
    //      (row&7) on the global side for conflict-free readback. ----
    int iid3[3];
#pragma unroll
    for (int k = 0; k < 3; k++) {
        const int s = w + 4 * k;
        const int r = 4 * s + (lane >> 4);
        iid3[k] = iidp[r < LL ? r : LL - 1];
    }
    int iid12 = 0;
    if (w == 0) {
        const int r = 48 + (lane >> 4);
        iid12 = iidp[r < LL ? r : LL - 1];
    }
#pragma unroll
    for (int k = 0; k < 3; k++) {
        const int s = w + 4 * k;
        const int r = 4 * s + (lane >> 4);
        const int j2 = (lane & 15) ^ (r & 7);
        glds16(item_table + (size_t)iid3[k] * DD + j2 * 4, sE + s * 256);
    }
    if (w == 0) {
        const int r = 48 + (lane >> 4);
        const int j2 = (lane & 15) ^ (r & 7);
        glds16(item_table + (size_t)iid12 * DD + j2 * 4, sE + 12 * 256);
    }

    // ---- small async loads, spread across waves ----
    if (w == 1)
        glds4(t2_ws + b * DD + (lane < LL ? lane : LL - 1), sT);
    if (w == 2) {
        const int tb = lane < NT ? lane : NT - 1;
        glds4(b2 + tgtp[tb], sB);
        const int uid = uid_g[b];
        glds4(user_table + (size_t)uid * DD + lane, sUu);
    }
    if (w == 3) {
        const int sl = 64 + lane;
        const int tb = sl < NT ? sl : NT - 1;
        glds4(b2 + tgtp[tb], sB + 64);
    }

    // ---- W2 gather straight to registers (issue now, consume in Phase C) ----
    int tt[7];
#pragma unroll
    for (int i = 0; i < 7; i++) {
        const int ts = i * 16 + gg;             // 0..111 (100..111 = pad)
        tt[i] = tgtp[ts < NT ? ts : NT - 1];
    }
    float4 wv[7];
#pragma unroll
    for (int i = 0; i < 7; i++)
        wv[i] = *(const float4*)(W2 + (size_t)tt[i] * DD + j * 4);

    // ---- per-b scalars ----
    float ufg4[4], igi4[4];
#pragma unroll
    for (int ni = 0; ni < 4; ni++) {
        ufg4[ni] = ufg_ws[b * DD + ni * 16 + c];
        igi4[ni] = igi[ni * 16 + c];
    }

    __syncthreads();   // drains vmcnt: all LDS staging + wv regs complete

    // ---- wb frags (8 KB table, L2-hot; loaded late to cut phase-A regs) ----
    bf16x8 wb[4][2];
#pragma unroll
    for (int ni = 0; ni < 4; ni++)
#pragma unroll
        for (int kf = 0; kf < 2; kf++)
            wb[ni][kf] = __builtin_bit_cast(bf16x8,
                *(const uint4*)(wiB + (ni * 16 + c) * DD + kf * 32 + q * 8));

    // ---- A-frags from LDS (deswizzled), invalid rows zeroed ----
    bf16x8 ea[2];
    {
        const int row = w * 16 + c;
        const int rr = (row < LL) ? row : 0;
        const float* rowp = sE + rr * DD;
        const int s7 = rr & 7;
#pragma unroll
        for (int kf = 0; kf < 2; kf++) {
            float tmp[8];
            const int ch0 = (kf * 8 + 2 * q) ^ s7;
            const int ch1 = (kf * 8 + 2 * q + 1) ^ s7;
            *(float4*)&tmp[0] = *(const float4*)(rowp + ch0 * 4);
            *(float4*)&tmp[4] = *(const float4*)(rowp + ch1 * 4);
            if (row >= LL) {
#pragma unroll
                for (int i = 0; i < 8; i++) tmp[i] = 0.f;
            }
            ea[kf] = cvt8f(tmp);
        }
    }

    // ---- union MFMA + fused per-reg epilogue ----
    float unum[4] = {0.f, 0.f, 0.f, 0.f};
    float sip[4]  = {0.f, 0.f, 0.f, 0.f};
    float isum = 0.f;
    {
        f32x4 acc[4];
#pragma unroll
        for (int ni = 0; ni < 4; ni++) {
            f32x4 a = {0.f, 0.f, 0.f, 0.f};
            a = __builtin_amdgcn_mfma_f32_16x16x32_bf16(ea[0], wb[ni][0], a, 0, 0, 0);
            a = __builtin_amdgcn_mfma_f32_16x16x32_bf16(ea[1], wb[ni][1], a, 0, 0, 0);
            acc[ni] = a;
        }
#pragma unroll
        for (int reg = 0; reg < 4; reg++) {
            const int l = w * 16 + q * 4 + reg;
            const int valid = (l < LL);
            const int lr = valid ? l : 0;
            const int s7 = lr & 7;
            float gd[4];
            float t1 = 0.f;
#pragma unroll
            for (int ni = 0; ni < 4; ni++) {
                const int phys = (4 * ni + (c >> 2)) ^ s7;
                const float ev = sE[lr * DD + phys * 4 + (c & 3)];
                const float e = valid ? ev : 0.f;
                const float g = sigmoidf_(acc[ni][reg] + ufg4[ni]);
                gd[ni] = e * g;
                t1 += gd[ni] * igi4[ni];
                sip[ni] += e;
            }
            t1 += __shfl_xor(t1, 1); t1 += __shfl_xor(t1, 2);
            t1 += __shfl_xor(t1, 4); t1 += __shfl_xor(t1, 8);
            const float inst = valid ? sigmoidf_(t1 + sT[lr]) : 0.f;
            isum += inst;
#pragma unroll
            for (int ni = 0; ni < 4; ni++)
                unum[ni] += gd[ni] * inst;
        }
    }

    // intra-wave: sum over q groups, then pick ni == q -> value for d = lane
#pragma unroll
    for (int ni = 0; ni < 4; ni++) {
        unum[ni] += __shfl_xor(unum[ni], 16); unum[ni] += __shfl_xor(unum[ni], 32);
        sip[ni]  += __shfl_xor(sip[ni], 16);  sip[ni]  += __shfl_xor(sip[ni], 32);
    }
    isum += __shfl_xor(isum, 16); isum += __shfl_xor(isum, 32);

    const float un = (q == 0) ? unum[0] : (q == 1) ? unum[1] : (q == 2) ? unum[2] : unum[3];
    const float si = (q == 0) ? sip[0]  : (q == 1) ? sip[1]  : (q == 2) ? sip[2]  : sip[3];
    sU[w * DD + lane] = un;
    sS[w * DD + lane] = si;
    if (lane == 0) sI[w] = isum;
    __syncthreads();

    // ---- redundant all-thread reduce -> vr (user-vector slice for dims j*4..) ----
    float4 vr;
    {
        const float4 u0 = *(const float4*)&sU[0 * DD + j * 4];
        const float4 u1 = *(const float4*)&sU[1 * DD + j * 4];
        const float4 u2 = *(const float4*)&sU[2 * DD + j * 4];
        const float4 u3 = *(const float4*)&sU[3 * DD + j * 4];
        const float4 s0 = *(const float4*)&sS[0 * DD + j * 4];
        const float4 s1 = *(const float4*)&sS[1 * DD + j * 4];
        const float4 s2 = *(const float4*)&sS[2 * DD + j * 4];
        const float4 s3 = *(const float4*)&sS[3 * DD + j * 4];
        const float4 uu = *(const float4*)&sUu[j * 4];
        const float rist = __builtin_amdgcn_rcpf(sI[0] + sI[1] + sI[2] + sI[3]);
        vr.x = uu.x + (u0.x + u1.x + u2.x + u3.x) * rist + (s0.x + s1.x + s2.x + s3.x);
        vr.y = uu.y + (u0.y + u1.y + u2.y + u3.y) * rist + (s0.y + s1.y + s2.y + s3.y);
        vr.z = uu.z + (u0.z + u1.z + u2.z + u3.z) * rist + (s0.z + s1.z + s2.z + s3.z);
        vr.w = uu.w + (u0.w + u1.w + u2.w + u3.w) * rist + (s0.w + s1.w + s2.w + s3.w);
    }

    // ---- scoring from registers: 16 lanes per target slot, 7 slots/group ----
#pragma unroll
    for (int i = 0; i < 7; i++) {
        const int ts = i * 16 + gg;
        float s = wv[i].x * vr.x + wv[i].y * vr.y + wv[i].z * vr.z + wv[i].w * vr.w;
        s += __shfl_xor(s, 1); s += __shfl_xor(s, 2);
        s += __shfl_xor(s, 4); s += __shfl_xor(s, 8);
        if (j == 0 && ts < NT) sOut[ts] = s + sB[ts];
    }
    __syncthreads();
    if (tid < NT) out[b * NT + tid] = sOut[tid];
}

// ===========================================================================
extern "C" void kernel_launch(void* const* d_in, const int* in_sizes, int n_in,
                              void* d_out, int out_size, void* d_ws, size_t ws_size,
                              hipStream_t stream)
{
    const int* user_ids        = (const int*)d_in[0];
    const int* item_seq_ids    = (const int*)d_in[1];
    const int* target_item_ids = (const int*)d_in[2];
    const float* user_tab      = (const float*)d_in[3];
    const float* item_tab      = (const float*)d_in[4];
    const float* W2_tab        = (const float*)d_in[5];
    const float* b2_tab        = (const float*)d_in[6];
    const float* fg_item_W     = (const float*)d_in[7];
    const float* fg_item_b     = (const float*)d_in[8];
    const float* fg_user_W     = (const float*)d_in[9];
    const float* fg_user_b     = (const float*)d_in[10];
    const float* igi           = (const float*)d_in[11];
    const float* igu           = (const float*)d_in[12];
    float* out = (float*)d_out;

    float* ufg_ws = (float*)d_ws;                       // [4096][64] f32
    float* t2_ws  = ufg_ws + NB * DD;                   // [4096][64] f32
    unsigned short* wiB_ws = (unsigned short*)(t2_ws + NB * DD);  // [64][64] bf16

    k0_user<<<257, 128, 0, stream>>>(user_ids, user_tab, fg_user_W, fg_user_b,
                                     fg_item_b, igu, fg_item_W,
                                     ufg_ws, t2_ws, wiB_ws);
    k1_fused<<<NB, 256, 0, stream>>>(user_ids, item_seq_ids, target_item_ids,
                                     user_tab, item_tab, W2_tab, b2_tab,
                                     wiB_ws, igi, ufg_ws, t2_ws, out);
}

// Round 3
// 153.606 us; speedup vs baseline: 1.0929x; 1.0062x over previous
//
#include <hip/hip_runtime.h>

// Problem constants
#define DD 64
#define LL 50
#define NB 4096
#define NT 100

typedef __attribute__((ext_vector_type(8))) __bf16 bf16x8;
typedef __attribute__((ext_vector_type(4))) float f32x4;

__device__ __forceinline__ float sigmoidf_(float x) {
    // v_rcp_f32 (~1ulp) instead of precise-division sequence (~10 instrs)
    return __builtin_amdgcn_rcpf(1.0f + __expf(-x));
}
// round-half-up f32->bf16, pack two into one u32 (hi -> upper 16)  [k0 path]
__device__ __forceinline__ unsigned pack_bf16(float hi, float lo) {
    union { float f; unsigned u; } a, b;
    a.f = hi; b.f = lo;
    return ((a.u + 0x8000u) & 0xffff0000u) | ((b.u + 0x8000u) >> 16);
}
__device__ __forceinline__ uint4 cvt8u(const float* f) {
    uint4 r;
    r.x = pack_bf16(f[1], f[0]);
    r.y = pack_bf16(f[3], f[2]);
    r.z = pack_bf16(f[5], f[4]);
    r.w = pack_bf16(f[7], f[6]);
    return r;
}
__device__ __forceinline__ bf16x8 cvt8(const float* f) {
    return __builtin_bit_cast(bf16x8, cvt8u(f));
}
// HW packed RNE convert: dst.lo = bf16(lo), dst.hi = bf16(hi)  [k1 path]
__device__ __forceinline__ unsigned cvtpk(float lo, float hi) {
    unsigned r;
    asm("v_cvt_pk_bf16_f32 %0, %1, %2" : "=v"(r) : "v"(lo), "v"(hi));
    return r;
}
__device__ __forceinline__ bf16x8 cvt8f(const float* f) {
    uint4 r;
    r.x = cvtpk(f[0], f[1]);
    r.y = cvtpk(f[2], f[3]);
    r.z = cvtpk(f[4], f[5]);
    r.w = cvtpk(f[6], f[7]);
    return __builtin_bit_cast(bf16x8, r);
}
// async global->LDS: wave-uniform LDS base + lane*size (gfx950)
__device__ __forceinline__ void glds16(const float* g, float* l) {
    __builtin_amdgcn_global_load_lds(
        (const __attribute__((address_space(1))) void*)g,
        (__attribute__((address_space(3))) void*)l, 16, 0, 0);
}
__device__ __forceinline__ void glds4(const float* g, float* l) {
    __builtin_amdgcn_global_load_lds(
        (const __attribute__((address_space(1))) void*)g,
        (__attribute__((address_space(3))) void*)l, 4, 0, 0);
}

// ===========================================================================
// K0: blocks 0..255: batched user GEMM (16 users/block, 2 waves: wave 0 does
//     ni 0..3 (fg_user_W), wave 1 does ni 4..7 (inst_gate_user)).
//     block 256: pack fg_item_W -> bf16 row-major (k1 reads frags directly).
// ===========================================================================
__global__ __launch_bounds__(128) void k0_user(
    const int* __restrict__ uid_g, const float* __restrict__ user_table,
    const float* __restrict__ Wu, const float* __restrict__ bu,
    const float* __restrict__ bi, const float* __restrict__ igu,
    const float* __restrict__ Wi,
    float* __restrict__ ufg_ws, float* __restrict__ t2_ws,
    unsigned short* __restrict__ wiB_ws)
{
    if (blockIdx.x == 256) {   // Wi -> bf16 pack (one wave only)
        if (threadIdx.x >= 64) return;
        const int n = threadIdx.x;
        float tmp[64];
#pragma unroll
        for (int c4 = 0; c4 < 16; c4++)
            *(float4*)&tmp[c4 * 4] = *(const float4*)(Wi + n * DD + c4 * 4);
#pragma unroll
        for (int ch = 0; ch < 8; ch++)
            *(uint4*)(wiB_ws + n * DD + ch * 8) = cvt8u(tmp + ch * 8);
        return;
    }

    const int lane = threadIdx.x & 63;
    const int wv = threadIdx.x >> 6;         // wave 0: ni 0..3, wave 1: ni 4..7
    const int c = lane & 15, q = lane >> 4;
    const int uid = uid_g[blockIdx.x * 16 + c];
    const float* urow = user_table + (size_t)uid * DD;

    bf16x8 af[2];
#pragma unroll
    for (int kf = 0; kf < 2; kf++) {
        float tmp[8];
        *(float4*)&tmp[0] = *(const float4*)(urow + kf * 32 + q * 8);
        *(float4*)&tmp[4] = *(const float4*)(urow + kf * 32 + q * 8 + 4);
        af[kf] = cvt8(tmp);
    }

#pragma unroll
    for (int ni0 = 0; ni0 < 4; ni0++) {
        const int ni = wv * 4 + ni0;
        f32x4 a = {0.f, 0.f, 0.f, 0.f};
#pragma unroll
        for (int kf = 0; kf < 2; kf++) {
            const int k0 = kf * 32 + q * 8;
            float tmp[8];
            if (ni < 4) {
                const float* src = Wu + (ni * 16 + c) * DD + k0;
                *(float4*)&tmp[0] = *(const float4*)src;
                *(float4*)&tmp[4] = *(const float4*)(src + 4);
            } else {
                const int l = ni * 16 + c - 64;
#pragma unroll
                for (int j = 0; j < 8; j++)
                    tmp[j] = (l < LL) ? igu[(k0 + j) * LL + l] : 0.f;
            }
            a = __builtin_amdgcn_mfma_f32_16x16x32_bf16(af[kf], cvt8(tmp), a, 0, 0, 0);
        }
        const int n = ni * 16 + c;
#pragma unroll
        for (int reg = 0; reg < 4; reg++) {
            const int bo = blockIdx.x * 16 + q * 4 + reg;
            if (n < DD)           ufg_ws[bo * DD + n] = a[reg] + bu[n] + bi[n];
            else if (n < DD + LL) t2_ws[bo * DD + (n - DD)] = a[reg];
        }
    }
}

// ===========================================================================
// K1F v3: fused union + scoring; WAVE-DECOUPLED phases A/B.
//   Wave w only ever touches item rows w*16..w*16+15 (A-frag row = w*16+c,
//   epilogue rows = w*16+q*4+reg) -> item tile is wave-PRIVATE. Each wave:
//     issue own 4 glds16 (item quadrant) + W2 regs + t2 float4 + wb/scalars,
//     asm s_waitcnt vmcnt(0) + sched_barrier(0)   (rule 18; no __syncthreads)
//     -> phase B independently. 32 independent wave streams/CU instead of
//   8 lockstepped blocks; the asm "memory" clobber also pins the W2 loads
//   before the wait (true prefetch — round 2's were likely sunk to phase C).
//   Only 2 barriers remain: cross-wave reduce, and sOut staging.
// ===========================================================================
__global__ __launch_bounds__(256, 4) void k1_fused(
    const int* __restrict__ uid_g, const int* __restrict__ iid_g,
    const int* __restrict__ tgt_g,
    const float* __restrict__ user_table, const float* __restrict__ item_table,
    const float* __restrict__ W2, const float* __restrict__ b2,
    const unsigned short* __restrict__ wiB, const float* __restrict__ igi,
    const float* __restrict__ ufg_ws, const float* __restrict__ t2_ws,
    float* __restrict__ out)
{
    const int tid = threadIdx.x;
    const int lane = tid & 63;
    const int w = tid >> 6;                 // wave id 0..3 == union mi
    const int c = lane & 15, q = lane >> 4;
    const int j = tid & 15, gg = tid >> 4;  // scoring: 16 groups of 16 lanes
    const int b = blockIdx.x;

    __shared__ __align__(16) float sE[4][16 * DD];  // wave-private item quadrants
    __shared__ __align__(16) float sB[128];         // b2 staged
    __shared__ __align__(16) float sUu[DD];         // user row
    __shared__ __align__(16) float sU[4 * DD];      // per-wave unum partials
    __shared__ __align__(16) float sS[4 * DD];      // per-wave sip partials
    __shared__ float sI[4];                         // per-wave isum partials
    __shared__ float sOut[112];

    const int* iidp = iid_g + b * LL;
    const int* tgtp = tgt_g + b * NT;
    float* sEw = sE[w];

    // ---- item ids for THIS wave's 16 rows (clamped) ----
    int iid4[4];
#pragma unroll
    for (int s = 0; s < 4; s++) {
        const int r = w * 16 + 4 * s + (lane >> 4);
        iid4[s] = iidp[r < LL ? r : LL - 1];
    }
    // ---- tgt ids (group-major, for W2 prefetch) ----
    int tt[7];
#pragma unroll
    for (int i = 0; i < 7; i++) {
        const int ts = i * 16 + gg;             // 0..111 (100..111 = pad)
        tt[i] = tgtp[ts < NT ? ts : NT - 1];
    }

    // ---- async item gather into own quadrant: local rows 4s..4s+3, 16B
    //      chunks XOR-swizzled by (local_row & 7) (== global&7, w*16%8==0) ----
#pragma unroll
    for (int s = 0; s < 4; s++) {
        const int rl = 4 * s + (lane >> 4);
        const int j2 = (lane & 15) ^ (rl & 7);
        glds16(item_table + (size_t)iid4[s] * DD + j2 * 4, sEw + s * 256);
    }

    // ---- W2 prefetch to regs (pinned before the waitcnt below) ----
    float4 wv[7];
#pragma unroll
    for (int i = 0; i < 7; i++)
        wv[i] = *(const float4*)(W2 + (size_t)tt[i] * DD + j * 4);

    // ---- small staged loads, spread across waves ----
    if (w == 1) {
        const int uid = uid_g[b];
        glds4(user_table + (size_t)uid * DD + lane, sUu);
    }
    if (w == 2) {
        const int tb = lane < NT ? lane : NT - 1;
        glds4(b2 + tgtp[tb], sB);
    }
    if (w == 3) {
        const int sl = 64 + lane;
        const int tb = sl < NT ? sl : NT - 1;
        glds4(b2 + tgtp[tb], sB + 64);
    }

    // ---- per-b scalars + t2 slice (float4, no LDS round-trip) ----
    float ufg4[4], igi4[4];
#pragma unroll
    for (int ni = 0; ni < 4; ni++) {
        ufg4[ni] = ufg_ws[b * DD + ni * 16 + c];
        igi4[ni] = igi[ni * 16 + c];
    }
    const float4 t2v = *(const float4*)(t2_ws + b * DD + w * 16 + q * 4);
    float t2a[4] = {t2v.x, t2v.y, t2v.z, t2v.w};

    // ---- wb frags (8 KB table, L2-hot) ----
    bf16x8 wb[4][2];
#pragma unroll
    for (int ni = 0; ni < 4; ni++)
#pragma unroll
        for (int kf = 0; kf < 2; kf++)
            wb[ni][kf] = __builtin_bit_cast(bf16x8,
                *(const uint4*)(wiB + (ni * 16 + c) * DD + kf * 32 + q * 8));

    // ---- wave-local drain: own glds + all reg loads complete; no barrier.
    //      "memory" clobber pins load issue above; sched_barrier stops ds_read
    //      hoisting past the wait (guide rule 18). ----
    asm volatile("s_waitcnt vmcnt(0)" ::: "memory");
    __builtin_amdgcn_sched_barrier(0);

    // ---- A-frags from own quadrant (deswizzled), invalid rows zeroed ----
    bf16x8 ea[2];
    {
        const int grow = w * 16 + c;
        const float* rowp = sEw + c * DD;
        const int s7 = c & 7;
#pragma unroll
        for (int kf = 0; kf < 2; kf++) {
            float tmp[8];
            const int ch0 = (kf * 8 + 2 * q) ^ s7;
            const int ch1 = (kf * 8 + 2 * q + 1) ^ s7;
            *(float4*)&tmp[0] = *(const float4*)(rowp + ch0 * 4);
            *(float4*)&tmp[4] = *(const float4*)(rowp + ch1 * 4);
            if (grow >= LL) {
#pragma unroll
                for (int i = 0; i < 8; i++) tmp[i] = 0.f;
            }
            ea[kf] = cvt8f(tmp);
        }
    }

    // ---- union MFMA + fused per-reg epilogue (all reads wave-private) ----
    float unum[4] = {0.f, 0.f, 0.f, 0.f};
    float sip[4]  = {0.f, 0.f, 0.f, 0.f};
    float isum = 0.f;
    {
        f32x4 acc[4];
#pragma unroll
        for (int ni = 0; ni < 4; ni++) {
            f32x4 a = {0.f, 0.f, 0.f, 0.f};
            a = __builtin_amdgcn_mfma_f32_16x16x32_bf16(ea[0], wb[ni][0], a, 0, 0, 0);
            a = __builtin_amdgcn_mfma_f32_16x16x32_bf16(ea[1], wb[ni][1], a, 0, 0, 0);
            acc[ni] = a;
        }
#pragma unroll
        for (int reg = 0; reg < 4; reg++) {
            const int lrl = q * 4 + reg;            // local row in quadrant
            const int valid = (w * 16 + lrl < LL);
            const int s7 = lrl & 7;
            float gd[4];
            float t1 = 0.f;
#pragma unroll
            for (int ni = 0; ni < 4; ni++) {
                const int phys = (4 * ni + (c >> 2)) ^ s7;
                const float ev = sEw[lrl * DD + phys * 4 + (c & 3)];
                const float e = valid ? ev : 0.f;
                const float g = sigmoidf_(acc[ni][reg] + ufg4[ni]);
                gd[ni] = e * g;
                t1 += gd[ni] * igi4[ni];
                sip[ni] += e;
            }
            t1 += __shfl_xor(t1, 1); t1 += __shfl_xor(t1, 2);
            t1 += __shfl_xor(t1, 4); t1 += __shfl_xor(t1, 8);
            const float inst = valid ? sigmoidf_(t1 + t2a[reg]) : 0.f;
            isum += inst;
#pragma unroll
            for (int ni = 0; ni < 4; ni++)
                unum[ni] += gd[ni] * inst;
        }
    }

    // intra-wave: sum over q groups, then pick ni == q -> value for d = lane
#pragma unroll
    for (int ni = 0; ni < 4; ni++) {
        unum[ni] += __shfl_xor(unum[ni], 16); unum[ni] += __shfl_xor(unum[ni], 32);
        sip[ni]  += __shfl_xor(sip[ni], 16);  sip[ni]  += __shfl_xor(sip[ni], 32);
    }
    isum += __shfl_xor(isum, 16); isum += __shfl_xor(isum, 32);

    const float un = (q == 0) ? unum[0] : (q == 1) ? unum[1] : (q == 2) ? unum[2] : unum[3];
    const float si = (q == 0) ? sip[0]  : (q == 1) ? sip[1]  : (q == 2) ? sip[2]  : sip[3];
    sU[w * DD + lane] = un;
    sS[w * DD + lane] = si;
    if (lane == 0) sI[w] = isum;
    __syncthreads();   // barrier 1: cross-wave reduce (also orders sUu/sB)

    // ---- redundant all-thread reduce -> vr (user-vector slice dims j*4..) ----
    float4 vr;
    {
        const float4 u0 = *(const float4*)&sU[0 * DD + j * 4];
        const float4 u1 = *(const float4*)&sU[1 * DD + j * 4];
        const float4 u2 = *(const float4*)&sU[2 * DD + j * 4];
        const float4 u3 = *(const float4*)&sU[3 * DD + j * 4];
        const float4 s0 = *(const float4*)&sS[0 * DD + j * 4];
        const float4 s1 = *(const float4*)&sS[1 * DD + j * 4];
        const float4 s2 = *(const float4*)&sS[2 * DD + j * 4];
        const float4 s3 = *(const float4*)&sS[3 * DD + j * 4];
        const float4 uu = *(const float4*)&sUu[j * 4];
        const float rist = __builtin_amdgcn_rcpf(sI[0] + sI[1] + sI[2] + sI[3]);
        vr.x = uu.x + (u0.x + u1.x + u2.x + u3.x) * rist + (s0.x + s1.x + s2.x + s3.x);
        vr.y = uu.y + (u0.y + u1.y + u2.y + u3.y) * rist + (s0.y + s1.y + s2.y + s3.y);
        vr.z = uu.z + (u0.z + u1.z + u2.z + u3.z) * rist + (s0.z + s1.z + s2.z + s3.z);
        vr.w = uu.w + (u0.w + u1.w + u2.w + u3.w) * rist + (s0.w + s1.w + s2.w + s3.w);
    }

    // ---- scoring from prefetched registers ----
#pragma unroll
    for (int i = 0; i < 7; i++) {
        const int ts = i * 16 + gg;
        float s = wv[i].x * vr.x + wv[i].y * vr.y + wv[i].z * vr.z + wv[i].w * vr.w;
        s += __shfl_xor(s, 1); s += __shfl_xor(s, 2);
        s += __shfl_xor(s, 4); s += __shfl_xor(s, 8);
        if (j == 0 && ts < NT) sOut[ts] = s + sB[ts];
    }
    __syncthreads();   // barrier 2: sOut staging
    if (tid < NT) out[b * NT + tid] = sOut[tid];
}

// ===========================================================================
extern "C" void kernel_launch(void* const* d_in, const int* in_sizes, int n_in,
                              void* d_out, int out_size, void* d_ws, size_t ws_size,
                              hipStream_t stream)
{
    const int* user_ids        = (const int*)d_in[0];
    const int* item_seq_ids    = (const int*)d_in[1];
    const int* target_item_ids = (const int*)d_in[2];
    const float* user_tab      = (const float*)d_in[3];
    const float* item_tab      = (const float*)d_in[4];
    const float* W2_tab        = (const float*)d_in[5];
    const float* b2_tab        = (const float*)d_in[6];
    const float* fg_item_W     = (const float*)d_in[7];
    const float* fg_item_b     = (const float*)d_in[8];
    const float* fg_user_W     = (const float*)d_in[9];
    const float* fg_user_b     = (const float*)d_in[10];
    const float* igi           = (const float*)d_in[11];
    const float* igu           = (const float*)d_in[12];
    float* out = (float*)d_out;

    float* ufg_ws = (float*)d_ws;                       // [4096][64] f32
    float* t2_ws  = ufg_ws + NB * DD;                   // [4096][64] f32
    unsigned short* wiB_ws = (unsigned short*)(t2_ws + NB * DD);  // [64][64] bf16

    k0_user<<<257, 128, 0, stream>>>(user_ids, user_tab, fg_user_W, fg_user_b,
                                     fg_item_b, igu, fg_item_W,
                                     ufg_ws, t2_ws, wiB_ws);
    k1_fused<<<NB, 256, 0, stream>>>(user_ids, item_seq_ids, target_item_ids,
                                     user_tab, item_tab, W2_tab, b2_tab,
                                     wiB_ws, igi, ufg_ws, t2_ws, out);
}